// Round 1
// baseline (123.143 us; speedup 1.0000x reference)
//
#include <hip/hip_runtime.h>
#include <hip/hip_bf16.h>

#define S_LEN 2048
#define DH    64
#define NBH   32
#define BQ    64
#define KBLK  64
#define SCALE 0.125f
#define PSTR  72   // P_lds row stride in ushort elems (64 + 8 pad)

typedef short v8s __attribute__((ext_vector_type(8)));
typedef float v4f __attribute__((ext_vector_type(4)));

__device__ __forceinline__ unsigned short f2bf(float f){
  union { float f; unsigned int u; } v; v.f = f;
  return (unsigned short)((v.u + 0x7FFFu + ((v.u >> 16) & 1u)) >> 16);
}

// ---------------- pre-pass: K fp32 -> bf16 ----------------
__global__ __launch_bounds__(256) void cvt_bf16(const float* __restrict__ in,
                                                unsigned short* __restrict__ out){
  int i = (blockIdx.x * 256 + threadIdx.x) * 4;
  float4 v = *(const float4*)(in + i);
  ushort4 o;
  o.x = f2bf(v.x); o.y = f2bf(v.y); o.z = f2bf(v.z); o.w = f2bf(v.w);
  *(ushort4*)(out + i) = o;
}

// ---------------- pre-pass: V fp32 [bh][k][d] -> bf16 VT [bh][d][k] ----------------
__global__ __launch_bounds__(256) void trans_v(const float* __restrict__ V,
                                               unsigned short* __restrict__ VT){
  __shared__ unsigned short t[DH][65];
  const int bh = blockIdx.y;
  const int k0 = blockIdx.x * 64;
  const float* src = V + (size_t)(bh * S_LEN + k0) * DH;
  #pragma unroll
  for (int i = 0; i < 16; ++i){
    int li = i * 256 + threadIdx.x;
    int r = li >> 6, c = li & 63;          // r = k-row, c = d
    t[c][r] = f2bf(src[li]);
  }
  __syncthreads();
  unsigned short* dst = VT + (size_t)bh * DH * S_LEN + k0;
  #pragma unroll
  for (int i = 0; i < 16; ++i){
    int li = i * 256 + threadIdx.x;
    int d = li >> 6, k = li & 63;
    dst[(size_t)d * S_LEN + k] = t[d][k];
  }
}

// ---------------- main flash-attention forward ----------------
// grid (S/BQ, NBH), 256 threads = 4 waves; wave w owns q rows qw0..qw0+15.
// S^T = K*Q^T via mfma_16x16x32_bf16 (C/D: col=lane&15=q, row=4g+reg=k).
__global__ __launch_bounds__(256, 2) void fa_fwd(
    const float* __restrict__ Q,
    const unsigned short* __restrict__ Kb,
    const unsigned short* __restrict__ VTb,
    float* __restrict__ O, float* __restrict__ L)
{
  __shared__ unsigned short K_lds[KBLK * DH];   // swizzled rows of 128B
  __shared__ unsigned short VT_lds[DH * KBLK];  // swizzled rows of 128B
  __shared__ unsigned short P_lds[4][16 * PSTR];

  const int tid  = threadIdx.x;
  const int w    = tid >> 6;
  const int lane = tid & 63;
  const int lq   = lane & 15;
  const int g    = lane >> 4;
  const int bh   = blockIdx.y;
  const int q0   = blockIdx.x * BQ;
  const int qw0  = q0 + w * 16;

  // hoist Q fragments (two d-halves), fp32 -> bf16
  v8s qf[2];
  {
    const float* qp = Q + (size_t)(bh * S_LEN + qw0 + lq) * DH + g * 8;
    #pragma unroll
    for (int h = 0; h < 2; ++h){
      float4 a = *(const float4*)(qp + h * 32);
      float4 b = *(const float4*)(qp + h * 32 + 4);
      v8s qv;
      qv[0]=(short)f2bf(a.x); qv[1]=(short)f2bf(a.y); qv[2]=(short)f2bf(a.z); qv[3]=(short)f2bf(a.w);
      qv[4]=(short)f2bf(b.x); qv[5]=(short)f2bf(b.y); qv[6]=(short)f2bf(b.z); qv[7]=(short)f2bf(b.w);
      qf[h] = qv;
    }
  }

  v4f zero = {0.f, 0.f, 0.f, 0.f};
  v4f acc[4];
  acc[0] = zero; acc[1] = zero; acc[2] = zero; acc[3] = zero;
  float m = -INFINITY, l = 0.f;

  const int ntiles = blockIdx.x + 1;
  char* kbase = (char*)K_lds;
  char* vbase = (char*)VT_lds;
  char* pbase = (char*)(&P_lds[w][0]);

  for (int t = 0; t < ntiles; ++t){
    const int kv0 = t * KBLK;
    __syncthreads();
    {
      // stage K tile [64][64] and VT tile [64][64] (bf16), XOR-swizzled
      const int r    = tid >> 2;
      const int c16  = (tid & 3) * 16;
      const int bofs = r * 128 + c16 * 2;
      const int swz  = (r & 7) << 4;
      const uint4* gk = (const uint4*)(Kb + (size_t)(bh * S_LEN + kv0 + r) * DH + c16);
      uint4 ka = gk[0];
      uint4 kb2 = gk[1];
      *(uint4*)(kbase + ((bofs     ) ^ swz)) = ka;
      *(uint4*)(kbase + ((bofs + 16) ^ swz)) = kb2;
      const uint4* gv = (const uint4*)(VTb + (size_t)(bh * DH + r) * S_LEN + kv0 + c16);
      uint4 va = gv[0];
      uint4 vb = gv[1];
      *(uint4*)(vbase + ((bofs     ) ^ swz)) = va;
      *(uint4*)(vbase + ((bofs + 16) ^ swz)) = vb;
    }
    __syncthreads();

    // ---- S^T = K * Q^T (4 subtiles of 16 k-rows) ----
    float p[4][4];
    float pmax = -INFINITY;
    const bool need_mask = (kv0 + KBLK - 1) > qw0;
    #pragma unroll
    for (int kb = 0; kb < 4; ++kb){
      v4f st = zero;
      #pragma unroll
      for (int h = 0; h < 2; ++h){
        const int row = kb * 16 + lq;
        v8s kf = *(const v8s*)(kbase + ((row * 128 + h * 64 + g * 16) ^ ((row & 7) << 4)));
        st = __builtin_amdgcn_mfma_f32_16x16x32_bf16(kf, qf[h], st, 0, 0, 0);
      }
      #pragma unroll
      for (int r = 0; r < 4; ++r){
        float s = st[r] * SCALE;
        if (need_mask){
          const int krow = kv0 + kb * 16 + g * 4 + r;
          if (krow > qw0 + lq) s = -INFINITY;
        }
        p[kb][r] = s;
        pmax = fmaxf(pmax, s);
      }
    }
    // row (q) statistics: reduce across the 4 lane-groups
    pmax = fmaxf(pmax, __shfl_xor(pmax, 16));
    pmax = fmaxf(pmax, __shfl_xor(pmax, 32));
    const float mn = fmaxf(m, pmax);
    const float sf = expf(m - mn);          // first tile: expf(-inf)=0
    float psum = 0.f;
    #pragma unroll
    for (int kb = 0; kb < 4; ++kb){
      #pragma unroll
      for (int r = 0; r < 4; ++r){
        const float pe = expf(p[kb][r] - mn);  // masked -> expf(-inf)=0
        p[kb][r] = pe;
        psum += pe;
      }
    }
    psum += __shfl_xor(psum, 16);
    psum += __shfl_xor(psum, 32);
    l = l * sf + psum;
    m = mn;

    // rescale O accumulator: acc rows live at q = 4g+reg; fetch sf per row
    float sfq[4];
    #pragma unroll
    for (int r = 0; r < 4; ++r) sfq[r] = __shfl(sf, g * 4 + r);
    #pragma unroll
    for (int db = 0; db < 4; ++db){
      #pragma unroll
      for (int r = 0; r < 4; ++r) acc[db][r] *= sfq[r];
    }

    // ---- P (bf16) through per-wave LDS to form PV A-fragments ----
    #pragma unroll
    for (int kb = 0; kb < 4; ++kb){
      ushort4 pk;
      pk.x = f2bf(p[kb][0]); pk.y = f2bf(p[kb][1]);
      pk.z = f2bf(p[kb][2]); pk.w = f2bf(p[kb][3]);
      // element [q=lq][k = kb*16 + 4g + r]
      *(ushort4*)(pbase + lq * (PSTR * 2) + kb * 32 + g * 8) = pk;
    }
    __threadfence_block();  // wave-local LDS RAW fence
    v8s pa[2];
    #pragma unroll
    for (int kh = 0; kh < 2; ++kh)
      pa[kh] = *(const v8s*)(pbase + lq * (PSTR * 2) + kh * 64 + g * 16);

    // ---- O += P * V ----
    #pragma unroll
    for (int db = 0; db < 4; ++db){
      #pragma unroll
      for (int kh = 0; kh < 2; ++kh){
        const int row = db * 16 + lq;
        v8s vf = *(const v8s*)(vbase + ((row * 128 + kh * 64 + g * 16) ^ ((row & 7) << 4)));
        acc[db] = __builtin_amdgcn_mfma_f32_16x16x32_bf16(pa[kh], vf, acc[db], 0, 0, 0);
      }
    }
  }

  // epilogue: normalize by l (per output row q = 4g+reg) and store O, L
  const float invl = 1.f / l;
  float ilq[4];
  #pragma unroll
  for (int r = 0; r < 4; ++r) ilq[r] = __shfl(invl, g * 4 + r);
  #pragma unroll
  for (int db = 0; db < 4; ++db){
    #pragma unroll
    for (int r = 0; r < 4; ++r){
      const int qrow = qw0 + g * 4 + r;
      O[(size_t)(bh * S_LEN + qrow) * DH + db * 16 + lq] = acc[db][r] * ilq[r];
    }
  }
  if (g == 0)
    L[(size_t)bh * S_LEN + qw0 + lq] = m + logf(l);
}

// ---------------- naive fallback (only if ws too small) ----------------
__global__ __launch_bounds__(64) void fa_naive(
    const float* __restrict__ Q, const float* __restrict__ K,
    const float* __restrict__ V, float* __restrict__ O, float* __restrict__ L)
{
  const int q  = blockIdx.x;
  const int bh = blockIdx.y;
  const int d  = threadIdx.x;
  const float qv = Q[(size_t)(bh * S_LEN + q) * DH + d];
  float m = -INFINITY, l = 0.f, o = 0.f;
  for (int k = 0; k <= q; ++k){
    float s = qv * K[(size_t)(bh * S_LEN + k) * DH + d];
    #pragma unroll
    for (int off = 32; off > 0; off >>= 1) s += __shfl_xor(s, off);
    s *= SCALE;
    const float mn = fmaxf(m, s);
    const float sfc = expf(m - mn);
    const float pe = expf(s - mn);
    l = l * sfc + pe;
    o = o * sfc + pe * V[(size_t)(bh * S_LEN + k) * DH + d];
    m = mn;
  }
  O[(size_t)(bh * S_LEN + q) * DH + d] = o / l;
  if (d == 0) L[(size_t)bh * S_LEN + q] = m + logf(l);
}

extern "C" void kernel_launch(void* const* d_in, const int* in_sizes, int n_in,
                              void* d_out, int out_size, void* d_ws, size_t ws_size,
                              hipStream_t stream)
{
  (void)in_sizes; (void)n_in; (void)out_size;
  const float* Q = (const float*)d_in[0];
  const float* K = (const float*)d_in[1];
  const float* V = (const float*)d_in[2];
  float* O = (float*)d_out;
  float* L = O + (size_t)NBH * S_LEN * DH;

  const size_t half = (size_t)NBH * S_LEN * DH * sizeof(unsigned short); // 8 MiB
  if (ws_size >= 2 * half){
    unsigned short* Kb = (unsigned short*)d_ws;
    unsigned short* VT = Kb + (size_t)NBH * S_LEN * DH;
    cvt_bf16<<<dim3((NBH * S_LEN * DH) / (4 * 256)), 256, 0, stream>>>(K, Kb);
    trans_v<<<dim3(S_LEN / 64, NBH), 256, 0, stream>>>(V, VT);
    fa_fwd<<<dim3(S_LEN / BQ, NBH), 256, 0, stream>>>(Q, Kb, VT, O, L);
  } else {
    fa_naive<<<dim3(S_LEN, NBH), 64, 0, stream>>>(Q, K, V, O, L);
  }
}

// Round 3
// 102.672 us; speedup vs baseline: 1.1994x; 1.1994x over previous
//
#include <hip/hip_runtime.h>
#include <hip/hip_bf16.h>

#define S_LEN 2048
#define DH    64
#define NBH   32
#define BQ    64
#define KBLK  64
#define KSCALE 0.1803368801111f  /* (1/8) * log2(e) */
#define LN2    0.6931471805599453f

typedef short v4s __attribute__((ext_vector_type(4)));
typedef short v8s __attribute__((ext_vector_type(8)));
typedef float v4f __attribute__((ext_vector_type(4)));

__device__ __forceinline__ unsigned short f2bf(float f){
  union { float f; unsigned int u; } v; v.f = f;
  return (unsigned short)((v.u + 0x7FFFu + ((v.u >> 16) & 1u)) >> 16);
}

__device__ __forceinline__ void gld16(void* lds, const void* g){
  __builtin_amdgcn_global_load_lds(
      (const __attribute__((address_space(1))) unsigned int*)g,
      (__attribute__((address_space(3))) unsigned int*)lds, 16, 0, 0);
}

// ---------------- pre-pass: K fp32 -> bf16 ----------------
__global__ __launch_bounds__(256) void cvt_bf16(const float* __restrict__ in,
                                                unsigned short* __restrict__ out){
  int i = (blockIdx.x * 256 + threadIdx.x) * 4;
  float4 v = *(const float4*)(in + i);
  ushort4 o;
  o.x = f2bf(v.x); o.y = f2bf(v.y); o.z = f2bf(v.z); o.w = f2bf(v.w);
  *(ushort4*)(out + i) = o;
}

// ---------------- pre-pass: V fp32 [bh][k][d] -> bf16 VT [bh][d][k] ----------------
__global__ __launch_bounds__(256) void trans_v(const float* __restrict__ V,
                                               unsigned short* __restrict__ VT){
  __shared__ unsigned short t[DH][65];
  const int bh = blockIdx.y;
  const int k0 = blockIdx.x * 64;
  const float* src = V + (size_t)(bh * S_LEN + k0) * DH;
  #pragma unroll
  for (int i = 0; i < 16; ++i){
    int li = i * 256 + threadIdx.x;
    int r = li >> 6, c = li & 63;
    t[c][r] = f2bf(src[li]);
  }
  __syncthreads();
  unsigned short* dst = VT + (size_t)bh * DH * S_LEN + k0;
  #pragma unroll
  for (int i = 0; i < 16; ++i){
    int li = i * 256 + threadIdx.x;
    int d = li >> 6, k = li & 63;
    dst[(size_t)d * S_LEN + k] = t[d][k];
  }
}

// ---------------- main flash-attention forward ----------------
// grid (S/BQ, NBH), 256 threads = 4 waves; wave w owns q rows qw0..qw0+15.
// S^T = K*Q^T (16x16x32): C/D col=lane&15=q, row=4g+r=k-row.
// O^T = V^T*P^T (16x16x16 bf16_1k): B-fragment col=lane&15=q, k=4g+j == the
// S^T fragment the lane already holds -> P stays in registers.
__global__ __launch_bounds__(256, 4) void fa_fwd(
    const float* __restrict__ Q,
    const unsigned short* __restrict__ Kb,
    const unsigned short* __restrict__ VTb,
    float* __restrict__ O, float* __restrict__ L)
{
  __shared__ char smem[2][16384];   // [buf][ K 8KB | VT 8KB ]

  const int tid  = threadIdx.x;
  const int w    = tid >> 6;
  const int lane = tid & 63;
  const int lq   = lane & 15;
  const int g    = lane >> 4;
  const int bh   = blockIdx.y;
  const int q0   = blockIdx.x * BQ;
  const int qw0  = q0 + w * 16;
  const int ntiles = blockIdx.x + 1;

  // per-lane static staging offsets (in shorts) for the two 1KB chunks/wave.
  // dest byte x (linear); source column pre-swizzled with the same XOR the
  // compute-side reads apply (involution, rule 21).
  int kOff[2], vOff[2];
  #pragma unroll
  for (int i = 0; i < 2; ++i){
    int x    = w * 2048 + i * 1024 + lane * 16;
    int row  = x >> 7;
    int scol = (x & 127) ^ ((row & 7) << 4);
    kOff[i] = row * DH + (scol >> 1);
    vOff[i] = row * S_LEN + (scol >> 1);
  }
  const unsigned short* KbB = Kb  + (size_t)bh * S_LEN * DH;
  const unsigned short* VbB = VTb + (size_t)bh * DH * S_LEN;

  auto issue = [&](int kv, char* buf){
    #pragma unroll
    for (int i = 0; i < 2; ++i){
      gld16(buf        + w * 2048 + i * 1024, KbB + kv * DH + kOff[i]);
      gld16(buf + 8192 + w * 2048 + i * 1024, VbB + kv      + vOff[i]);
    }
  };

  // hoist Q fragments, pre-scaled by 1/sqrt(d)*log2(e), fp32 -> bf16
  v8s qf[2];
  {
    const float* qp = Q + (size_t)(bh * S_LEN + qw0 + lq) * DH + g * 8;
    #pragma unroll
    for (int h = 0; h < 2; ++h){
      float4 a = *(const float4*)(qp + h * 32);
      float4 b = *(const float4*)(qp + h * 32 + 4);
      v8s qv;
      qv[0]=(short)f2bf(a.x*KSCALE); qv[1]=(short)f2bf(a.y*KSCALE);
      qv[2]=(short)f2bf(a.z*KSCALE); qv[3]=(short)f2bf(a.w*KSCALE);
      qv[4]=(short)f2bf(b.x*KSCALE); qv[5]=(short)f2bf(b.y*KSCALE);
      qv[6]=(short)f2bf(b.z*KSCALE); qv[7]=(short)f2bf(b.w*KSCALE);
      qf[h] = qv;
    }
  }

  issue(0, smem[0]);   // prologue: tile 0 -> buf 0

  v4f zero = {0.f, 0.f, 0.f, 0.f};
  v4f acc[4];
  acc[0] = zero; acc[1] = zero; acc[2] = zero; acc[3] = zero;
  float m = -INFINITY, l = 0.f;

  for (int t = 0; t < ntiles; ++t){
    const int kv0 = t * KBLK;
    const int tn  = (t + 1 < ntiles) ? t + 1 : t;
    issue(tn * KBLK, smem[(t + 1) & 1]);           // prefetch next tile
    asm volatile("s_waitcnt vmcnt(4)" ::: "memory"); // current tile landed
    __builtin_amdgcn_s_barrier();
    __builtin_amdgcn_sched_barrier(0);

    const char* kbase = smem[t & 1];
    const char* vbase = smem[t & 1] + 8192;

    // ---- S^T = K * Q^T ----
    float p[4][4];
    float pmax = -INFINITY;
    const bool need_mask = (kv0 + KBLK - 1) > qw0;
    #pragma unroll
    for (int kb = 0; kb < 4; ++kb){
      v4f st = zero;
      #pragma unroll
      for (int h = 0; h < 2; ++h){
        const int row = kb * 16 + lq;
        v8s kf = *(const v8s*)(kbase + ((row * 128 + h * 64 + g * 16) ^ ((row & 7) << 4)));
        st = __builtin_amdgcn_mfma_f32_16x16x32_bf16(kf, qf[h], st, 0, 0, 0);
      }
      #pragma unroll
      for (int r = 0; r < 4; ++r){
        float s = st[r];                     // scale folded into Q
        if (need_mask){
          const int krow = kv0 + kb * 16 + g * 4 + r;
          if (krow > qw0 + lq) s = -INFINITY;
        }
        p[kb][r] = s;
        pmax = fmaxf(pmax, s);
      }
    }
    pmax = fmaxf(pmax, __shfl_xor(pmax, 16));
    pmax = fmaxf(pmax, __shfl_xor(pmax, 32));

    // online update with defer-max (THR=8 in log2 domain)
    if (!__all(pmax - m <= 8.0f)){
      const float mn = fmaxf(m, pmax);
      const float sf = exp2f(m - mn);        // first tile: exp2(-inf)=0
      #pragma unroll
      for (int db = 0; db < 4; ++db) acc[db] *= sf;
      l *= sf;
      m = mn;
    }
    float psum = 0.f;
    #pragma unroll
    for (int kb = 0; kb < 4; ++kb){
      #pragma unroll
      for (int r = 0; r < 4; ++r){
        const float pe = exp2f(p[kb][r] - m);   // masked -> 0
        p[kb][r] = pe;
        psum += pe;
      }
    }
    psum += __shfl_xor(psum, 16);
    psum += __shfl_xor(psum, 32);
    l += psum;

    // ---- O^T += V^T * P^T  (P stays in registers) ----
    #pragma unroll
    for (int kb = 0; kb < 4; ++kb){
      v4s pb;
      pb[0] = (short)f2bf(p[kb][0]); pb[1] = (short)f2bf(p[kb][1]);
      pb[2] = (short)f2bf(p[kb][2]); pb[3] = (short)f2bf(p[kb][3]);
      #pragma unroll
      for (int db = 0; db < 4; ++db){
        const int row = db * 16 + lq;
        v4s va = *(const v4s*)(vbase + ((row * 128 + kb * 32 + g * 8) ^ ((row & 7) << 4)));
        acc[db] = __builtin_amdgcn_mfma_f32_16x16x16bf16_1k(va, pb, acc[db], 0, 0, 0);
      }
    }
    __builtin_amdgcn_s_barrier();
    __builtin_amdgcn_sched_barrier(0);
  }

  // epilogue: O^T fragment -> O[q][d]; all stats are lane-local (q = lq)
  const float invl = 1.f / l;
  float* Op = O + ((size_t)bh * S_LEN + qw0 + lq) * DH + g * 4;
  #pragma unroll
  for (int db = 0; db < 4; ++db){
    v4f o = acc[db] * invl;
    *(v4f*)(Op + db * 16) = o;
  }
  if (g == 0)
    L[(size_t)bh * S_LEN + qw0 + lq] = m * LN2 + logf(l);
}

// ---------------- naive fallback (only if ws too small) ----------------
__global__ __launch_bounds__(64) void fa_naive(
    const float* __restrict__ Q, const float* __restrict__ K,
    const float* __restrict__ V, float* __restrict__ O, float* __restrict__ L)
{
  const int q  = blockIdx.x;
  const int bh = blockIdx.y;
  const int d  = threadIdx.x;
  const float qv = Q[(size_t)(bh * S_LEN + q) * DH + d];
  float m = -INFINITY, l = 0.f, o = 0.f;
  for (int k = 0; k <= q; ++k){
    float s = qv * K[(size_t)(bh * S_LEN + k) * DH + d];
    #pragma unroll
    for (int off = 32; off > 0; off >>= 1) s += __shfl_xor(s, off);
    s *= 0.125f;
    const float mn = fmaxf(m, s);
    const float sfc = expf(m - mn);
    const float pe = expf(s - mn);
    l = l * sfc + pe;
    o = o * sfc + pe * V[(size_t)(bh * S_LEN + k) * DH + d];
    m = mn;
  }
  O[(size_t)(bh * S_LEN + q) * DH + d] = o / l;
  if (d == 0) L[(size_t)bh * S_LEN + q] = m + logf(l);
}

extern "C" void kernel_launch(void* const* d_in, const int* in_sizes, int n_in,
                              void* d_out, int out_size, void* d_ws, size_t ws_size,
                              hipStream_t stream)
{
  (void)in_sizes; (void)n_in; (void)out_size;
  const float* Q = (const float*)d_in[0];
  const float* K = (const float*)d_in[1];
  const float* V = (const float*)d_in[2];
  float* O = (float*)d_out;
  float* L = O + (size_t)NBH * S_LEN * DH;

  const size_t half = (size_t)NBH * S_LEN * DH * sizeof(unsigned short); // 8 MiB
  if (ws_size >= 2 * half){
    unsigned short* Kb = (unsigned short*)d_ws;
    unsigned short* VT = Kb + (size_t)NBH * S_LEN * DH;
    cvt_bf16<<<dim3((NBH * S_LEN * DH) / (4 * 256)), 256, 0, stream>>>(K, Kb);
    trans_v<<<dim3(S_LEN / 64, NBH), 256, 0, stream>>>(V, VT);
    fa_fwd<<<dim3(S_LEN / BQ, NBH), 256, 0, stream>>>(Q, Kb, VT, O, L);
  } else {
    fa_naive<<<dim3(S_LEN, NBH), 64, 0, stream>>>(Q, K, V, O, L);
  }
}

// Round 4
// 65.935 us; speedup vs baseline: 1.8676x; 1.5572x over previous
//
#include <hip/hip_runtime.h>
#include <hip/hip_bf16.h>

#define S_LEN 2048
#define DH    64
#define NBH   32
#define BQ    64
#define KBLK  64
#define KSCALE 0.1803368801111f  /* (1/8) * log2(e) */
#define LN2    0.6931471805599453f

typedef short v4s __attribute__((ext_vector_type(4)));
typedef short v8s __attribute__((ext_vector_type(8)));
typedef float v4f __attribute__((ext_vector_type(4)));

__device__ __forceinline__ unsigned short f2bf(float f){
  union { float f; unsigned int u; } v; v.f = f;
  return (unsigned short)((v.u + 0x7FFFu + ((v.u >> 16) & 1u)) >> 16);
}

__device__ __forceinline__ void gld16(void* lds, const void* g){
  __builtin_amdgcn_global_load_lds(
      (const __attribute__((address_space(1))) unsigned int*)g,
      (__attribute__((address_space(3))) unsigned int*)lds, 16, 0, 0);
}

// ---------------- pre-pass: K fp32 -> bf16 ----------------
__global__ __launch_bounds__(256) void cvt_bf16(const float* __restrict__ in,
                                                unsigned short* __restrict__ out){
  int i = (blockIdx.x * 256 + threadIdx.x) * 4;
  float4 v = *(const float4*)(in + i);
  ushort4 o;
  o.x = f2bf(v.x); o.y = f2bf(v.y); o.z = f2bf(v.z); o.w = f2bf(v.w);
  *(ushort4*)(out + i) = o;
}

// ---------------- pre-pass: V fp32 [bh][k][d] -> bf16 VT [bh][d][k] ----------------
__global__ __launch_bounds__(256) void trans_v(const float* __restrict__ V,
                                               unsigned short* __restrict__ VT){
  __shared__ unsigned short t[DH][65];
  const int bh = blockIdx.y;
  const int k0 = blockIdx.x * 64;
  const float* src = V + (size_t)(bh * S_LEN + k0) * DH;
  #pragma unroll
  for (int i = 0; i < 16; ++i){
    int li = i * 256 + threadIdx.x;
    int r = li >> 6, c = li & 63;
    t[c][r] = f2bf(src[li]);
  }
  __syncthreads();
  unsigned short* dst = VT + (size_t)bh * DH * S_LEN + k0;
  #pragma unroll
  for (int i = 0; i < 16; ++i){
    int li = i * 256 + threadIdx.x;
    int d = li >> 6, k = li & 63;
    dst[(size_t)d * S_LEN + k] = t[d][k];
  }
}

// ---------------- main flash-attention forward ----------------
// 1D grid, heavy-first: bid -> (x = 31 - bid/32, bh = bid & 31).
// 256 threads = 4 waves; wave w owns q rows qw0..qw0+15.
// S^T = K*Q^T (16x16x32): C/D col=lane&15=q, row=4g+r=k-row.
// O^T = V^T*P^T (16x16x16 bf16_1k): B-fragment col=lane&15=q, k=4g+j == the
// S^T fragment the lane already holds -> P stays in registers.
__global__ __launch_bounds__(256, 4) void fa_fwd(
    const float* __restrict__ Q,
    const unsigned short* __restrict__ Kb,
    const unsigned short* __restrict__ VTb,
    float* __restrict__ O, float* __restrict__ L)
{
  __shared__ char smem[2][16384];   // [buf][ K 8KB | VT 8KB ]

  const int tid  = threadIdx.x;
  const int w    = tid >> 6;
  const int lane = tid & 63;
  const int lq   = lane & 15;
  const int g    = lane >> 4;
  const int bid  = blockIdx.x;
  const int x    = 31 - (bid >> 5);     // heavy blocks dispatch first
  const int bh   = bid & 31;
  const int q0   = x * BQ;
  const int qw0  = q0 + w * 16;
  const int ntiles = x + 1;

  // staging: per-lane dest (linear) + pre-swizzled source column (rule 21)
  int kOff[2], vOff[2];
  #pragma unroll
  for (int i = 0; i < 2; ++i){
    int xo   = w * 2048 + i * 1024 + lane * 16;
    int row  = xo >> 7;
    int scol = (xo & 127) ^ ((row & 7) << 4);
    kOff[i] = row * DH + (scol >> 1);
    vOff[i] = row * S_LEN + (scol >> 1);
  }
  const unsigned short* KbB = Kb  + (size_t)bh * S_LEN * DH;
  const unsigned short* VbB = VTb + (size_t)bh * DH * S_LEN;

  auto issue = [&](int kv, char* buf){
    #pragma unroll
    for (int i = 0; i < 2; ++i){
      gld16(buf        + w * 2048 + i * 1024, KbB + kv * DH + kOff[i]);
      gld16(buf + 8192 + w * 2048 + i * 1024, VbB + kv      + vOff[i]);
    }
  };

  // hoisted per-lane LDS read offsets (swz = (lq&7)<<4 loop-invariant,
  // since row&7 == lq&7 for every row this lane ever reads)
  const int swz = (lq & 7) << 4;
  int qkLo[2], pvLo[4];
  #pragma unroll
  for (int h = 0; h < 2; ++h) qkLo[h] = lq * 128 + ((h * 64 + g * 16) ^ swz);
  #pragma unroll
  for (int kb = 0; kb < 4; ++kb) pvLo[kb] = lq * 128 + ((kb * 32 + g * 8) ^ swz);

  // hoist Q fragments, pre-scaled by 1/sqrt(d)*log2(e), fp32 -> bf16
  v8s qf[2];
  {
    const float* qp = Q + (size_t)(bh * S_LEN + qw0 + lq) * DH + g * 8;
    #pragma unroll
    for (int h = 0; h < 2; ++h){
      float4 a = *(const float4*)(qp + h * 32);
      float4 b = *(const float4*)(qp + h * 32 + 4);
      v8s qv;
      qv[0]=(short)f2bf(a.x*KSCALE); qv[1]=(short)f2bf(a.y*KSCALE);
      qv[2]=(short)f2bf(a.z*KSCALE); qv[3]=(short)f2bf(a.w*KSCALE);
      qv[4]=(short)f2bf(b.x*KSCALE); qv[5]=(short)f2bf(b.y*KSCALE);
      qv[6]=(short)f2bf(b.z*KSCALE); qv[7]=(short)f2bf(b.w*KSCALE);
      qf[h] = qv;
    }
  }

  issue(0, smem[0]);   // prologue: tile 0 -> buf 0

  v4f zero = {0.f, 0.f, 0.f, 0.f};
  v4f acc[4];
  acc[0] = zero; acc[1] = zero; acc[2] = zero; acc[3] = zero;
  float m = -INFINITY, l = 0.f;   // l kept lane-partial; reduced in epilogue

  for (int t = 0; t < ntiles; ++t){
    const int kv0 = t * KBLK;
    const int tn  = (t + 1 < ntiles) ? t + 1 : t;
    issue(tn * KBLK, smem[(t + 1) & 1]);             // prefetch next tile
    asm volatile("s_waitcnt vmcnt(4)" ::: "memory"); // current tile landed
    __builtin_amdgcn_s_barrier();
    __builtin_amdgcn_sched_barrier(0);

    const char* kbase = smem[t & 1];
    const char* vbase = smem[t & 1] + 8192;

    // ---- S^T = K * Q^T ----
    float p[4][4];
    const bool need_mask = (kv0 + KBLK - 1) > qw0;
    __builtin_amdgcn_s_setprio(1);
    #pragma unroll
    for (int kb = 0; kb < 4; ++kb){
      v4f st = zero;
      #pragma unroll
      for (int h = 0; h < 2; ++h){
        v8s kf = *(const v8s*)(kbase + kb * 2048 + qkLo[h]);
        st = __builtin_amdgcn_mfma_f32_16x16x32_bf16(kf, qf[h], st, 0, 0, 0);
      }
      #pragma unroll
      for (int r = 0; r < 4; ++r){
        float s = st[r];                     // scale folded into Q
        if (need_mask){
          const int krow = kv0 + kb * 16 + g * 4 + r;
          if (krow > qw0 + lq) s = -INFINITY;
        }
        p[kb][r] = s;
      }
    }
    __builtin_amdgcn_s_setprio(0);

    // tree max over the 16 local scores
    float mx[4];
    #pragma unroll
    for (int kb = 0; kb < 4; ++kb)
      mx[kb] = fmaxf(fmaxf(p[kb][0], p[kb][1]), fmaxf(p[kb][2], p[kb][3]));
    float pmax = fmaxf(fmaxf(mx[0], mx[1]), fmaxf(mx[2], mx[3]));
    pmax = fmaxf(pmax, __shfl_xor(pmax, 16));
    pmax = fmaxf(pmax, __shfl_xor(pmax, 32));

    // online update with defer-max (THR=8 in log2 domain)
    if (!__all(pmax - m <= 8.0f)){
      const float mn = fmaxf(m, pmax);
      const float sf = exp2f(m - mn);        // first tile: exp2(-inf)=0
      #pragma unroll
      for (int db = 0; db < 4; ++db) acc[db] *= sf;
      l *= sf;
      m = mn;
    }
    #pragma unroll
    for (int kb = 0; kb < 4; ++kb){
      #pragma unroll
      for (int r = 0; r < 4; ++r){
        const float pe = exp2f(p[kb][r] - m);   // masked -> 0
        p[kb][r] = pe;
        l += pe;                                // lane-partial sum
      }
    }

    // ---- O^T += V^T * P^T  (P stays in registers) ----
    __builtin_amdgcn_s_setprio(1);
    #pragma unroll
    for (int kb = 0; kb < 4; ++kb){
      v4s pb;
      pb[0] = (short)f2bf(p[kb][0]); pb[1] = (short)f2bf(p[kb][1]);
      pb[2] = (short)f2bf(p[kb][2]); pb[3] = (short)f2bf(p[kb][3]);
      #pragma unroll
      for (int db = 0; db < 4; ++db){
        v4s va = *(const v4s*)(vbase + db * 2048 + pvLo[kb]);
        acc[db] = __builtin_amdgcn_mfma_f32_16x16x16bf16_1k(va, pb, acc[db], 0, 0, 0);
      }
    }
    __builtin_amdgcn_s_setprio(0);
    __builtin_amdgcn_s_barrier();
    __builtin_amdgcn_sched_barrier(0);
  }

  // epilogue: reduce l across the 4 lane-groups, then store O^T fragment, L
  l += __shfl_xor(l, 16);
  l += __shfl_xor(l, 32);
  const float invl = 1.f / l;
  float* Op = O + ((size_t)bh * S_LEN + qw0 + lq) * DH + g * 4;
  #pragma unroll
  for (int db = 0; db < 4; ++db){
    v4f o = acc[db] * invl;
    *(v4f*)(Op + db * 16) = o;
  }
  if (g == 0)
    L[(size_t)bh * S_LEN + qw0 + lq] = m * LN2 + logf(l);
}

// ---------------- naive fallback (only if ws too small) ----------------
__global__ __launch_bounds__(64) void fa_naive(
    const float* __restrict__ Q, const float* __restrict__ K,
    const float* __restrict__ V, float* __restrict__ O, float* __restrict__ L)
{
  const int q  = blockIdx.x;
  const int bh = blockIdx.y;
  const int d  = threadIdx.x;
  const float qv = Q[(size_t)(bh * S_LEN + q) * DH + d];
  float m = -INFINITY, l = 0.f, o = 0.f;
  for (int k = 0; k <= q; ++k){
    float s = qv * K[(size_t)(bh * S_LEN + k) * DH + d];
    #pragma unroll
    for (int off = 32; off > 0; off >>= 1) s += __shfl_xor(s, off);
    s *= 0.125f;
    const float mn = fmaxf(m, s);
    const float sfc = expf(m - mn);
    const float pe = expf(s - mn);
    l = l * sfc + pe;
    o = o * sfc + pe * V[(size_t)(bh * S_LEN + k) * DH + d];
    m = mn;
  }
  O[(size_t)(bh * S_LEN + q) * DH + d] = o / l;
  if (d == 0) L[(size_t)bh * S_LEN + q] = m + logf(l);
}

extern "C" void kernel_launch(void* const* d_in, const int* in_sizes, int n_in,
                              void* d_out, int out_size, void* d_ws, size_t ws_size,
                              hipStream_t stream)
{
  (void)in_sizes; (void)n_in; (void)out_size;
  const float* Q = (const float*)d_in[0];
  const float* K = (const float*)d_in[1];
  const float* V = (const float*)d_in[2];
  float* O = (float*)d_out;
  float* L = O + (size_t)NBH * S_LEN * DH;

  const size_t half = (size_t)NBH * S_LEN * DH * sizeof(unsigned short); // 8 MiB
  if (ws_size >= 2 * half){
    unsigned short* Kb = (unsigned short*)d_ws;
    unsigned short* VT = Kb + (size_t)NBH * S_LEN * DH;
    cvt_bf16<<<dim3((NBH * S_LEN * DH) / (4 * 256)), 256, 0, stream>>>(K, Kb);
    trans_v<<<dim3(S_LEN / 64, NBH), 256, 0, stream>>>(V, VT);
    fa_fwd<<<dim3((S_LEN / BQ) * NBH), 256, 0, stream>>>(Q, Kb, VT, O, L);
  } else {
    fa_naive<<<dim3(S_LEN, NBH), 64, 0, stream>>>(Q, K, V, O, L);
  }
}

// Round 5
// 56.582 us; speedup vs baseline: 2.1763x; 1.1653x over previous
//
#include <hip/hip_runtime.h>
#include <hip/hip_bf16.h>

#define S_LEN 2048
#define DH    64
#define NBH   32
#define KSCALE 0.1803368801111f  /* (1/8) * log2(e) */
#define LN2    0.6931471805599453f

typedef short v4s __attribute__((ext_vector_type(4)));
typedef short v8s __attribute__((ext_vector_type(8)));
typedef float v4f __attribute__((ext_vector_type(4)));

__device__ __forceinline__ unsigned short f2bf(float f){
  union { float f; unsigned int u; } v; v.f = f;
  return (unsigned short)((v.u + 0x7FFFu + ((v.u >> 16) & 1u)) >> 16);
}

__device__ __forceinline__ void gld16(void* lds, const void* g){
  __builtin_amdgcn_global_load_lds(
      (const __attribute__((address_space(1))) unsigned int*)g,
      (__attribute__((address_space(3))) unsigned int*)lds, 16, 0, 0);
}

// ---------------- pre-pass: K,V fp32 -> bf16 in MFMA-fragment order ----------
// Kf chunk layout (per bh, per 64-row tile t), 8KB:
//   byte (kb*2+h)*1024 + l*16 + j*2  =  K[t*64 + kb*16 + (l&15)][h*32 + (l>>4)*8 + j]
// Vf chunk layout, 8KB:
//   byte (db*2+kp)*1024 + l*16 + s*8 + j*2 = V[t*64 + kp*32 + s*16 + (l>>4)*4 + j][db*16 + (l&15)]
__global__ __launch_bounds__(256) void prep(const float* __restrict__ K,
                                            const float* __restrict__ V,
                                            unsigned short* __restrict__ Kf,
                                            unsigned short* __restrict__ Vf){
  __shared__ unsigned short s[64 * 72];
  const int t   = blockIdx.x;
  const int bh  = blockIdx.y;
  const int tid = threadIdx.x;

  // ---- K phase ----
  const float* Ksrc = K + ((size_t)bh * S_LEN + t * 64) * DH;
  #pragma unroll
  for (int i = 0; i < 4; ++i){
    int f = tid + i * 256;                 // float4 index
    float4 v = ((const float4*)Ksrc)[f];
    int row = f >> 4, col = (f & 15) * 4;
    ushort4 o; o.x = f2bf(v.x); o.y = f2bf(v.y); o.z = f2bf(v.z); o.w = f2bf(v.w);
    *(ushort4*)(&s[row * 72 + col]) = o;
  }
  __syncthreads();
  unsigned short* KfT = Kf + ((size_t)bh * 32 + t) * 4096;
  #pragma unroll
  for (int i = 0; i < 2; ++i){
    int item = tid + i * 256;
    int c = item >> 6, l = item & 63;
    int kb = c >> 1, h = c & 1;
    v8s frag = *(const v8s*)(&s[(kb * 16 + (l & 15)) * 72 + h * 32 + (l >> 4) * 8]);
    *(v8s*)(&KfT[c * 512 + l * 8]) = frag;
  }
  __syncthreads();

  // ---- V phase (transposed into LDS) ----
  const float* Vsrc = V + ((size_t)bh * S_LEN + t * 64) * DH;
  #pragma unroll
  for (int i = 0; i < 4; ++i){
    int f = tid + i * 256;
    float4 v = ((const float4*)Vsrc)[f];
    int k = f >> 4, d = (f & 15) * 4;
    s[(d + 0) * 72 + k] = f2bf(v.x);
    s[(d + 1) * 72 + k] = f2bf(v.y);
    s[(d + 2) * 72 + k] = f2bf(v.z);
    s[(d + 3) * 72 + k] = f2bf(v.w);
  }
  __syncthreads();
  unsigned short* VfT = Vf + ((size_t)bh * 32 + t) * 4096;
  #pragma unroll
  for (int i = 0; i < 2; ++i){
    int item = tid + i * 256;
    int c = item >> 6, l = item & 63;
    int db = c >> 1, kp = c & 1;
    int dd = db * 16 + (l & 15);
    int kk = kp * 32 + (l >> 4) * 4;
    v4s a = *(const v4s*)(&s[dd * 72 + kk]);        // s=0 half
    v4s b = *(const v4s*)(&s[dd * 72 + kk + 16]);   // s=1 half
    v8s fr; fr[0]=a[0]; fr[1]=a[1]; fr[2]=a[2]; fr[3]=a[3];
            fr[4]=b[0]; fr[5]=b[1]; fr[6]=b[2]; fr[7]=b[3];
    *(v8s*)(&VfT[c * 512 + l * 8]) = fr;
  }
}

// ---------------- main flash-attention forward ----------------
// grid (bh=32, pair=16), 512 threads = 8 waves.
// Waves 0-3 -> q-tile A = p, waves 4-7 -> q-tile B = 31-p (shared K/V staging;
// combined active duration ~33 tiles for every block -> balanced).
// S^T = K*Q^T (16x16x32): C/D col=lane&15=q, row=4g+r=k.
// O^T = V^T*P^T (16x16x16 bf16_1k): B-frag == S^T C-frag -> P stays in regs.
__global__ __launch_bounds__(512, 4) void fa_fwd(
    const float* __restrict__ Q,
    const unsigned short* __restrict__ Kf,
    const unsigned short* __restrict__ Vf,
    float* __restrict__ O, float* __restrict__ L)
{
  __shared__ char smem[2][16384];   // [buf][ K 8KB | V 8KB ]

  const int tid  = threadIdx.x;
  const int w    = tid >> 6;
  const int lane = tid & 63;
  const int lq   = lane & 15;
  const int g    = lane >> 4;
  const int bh   = blockIdx.x;
  const int p    = blockIdx.y;
  const int qt   = (w < 4) ? p : 31 - p;   // my q-tile index
  const int qw0  = qt * 64 + (w & 3) * 16; // my 16 q-rows
  const int M    = 32 - p;                 // tiles staged by this block

  const unsigned short* KfB = Kf + (size_t)bh * 32 * 4096;
  const unsigned short* VfB = Vf + (size_t)bh * 32 * 4096;
  const int srcOff = w * 512 + lane * 8;   // shorts: w*1024B + lane*16B

  auto issue = [&](int t, char* buf){
    gld16(buf        + w * 1024, KfB + (size_t)t * 4096 + srcOff);
    gld16(buf + 8192 + w * 1024, VfB + (size_t)t * 4096 + srcOff);
  };

  // hoist Q fragments, pre-scaled by 1/sqrt(d)*log2(e), fp32 -> bf16
  v8s qf[2];
  {
    const float* qp = Q + (size_t)(bh * S_LEN + qw0 + lq) * DH + g * 8;
    #pragma unroll
    for (int h = 0; h < 2; ++h){
      float4 a = *(const float4*)(qp + h * 32);
      float4 b = *(const float4*)(qp + h * 32 + 4);
      v8s qv;
      qv[0]=(short)f2bf(a.x*KSCALE); qv[1]=(short)f2bf(a.y*KSCALE);
      qv[2]=(short)f2bf(a.z*KSCALE); qv[3]=(short)f2bf(a.w*KSCALE);
      qv[4]=(short)f2bf(b.x*KSCALE); qv[5]=(short)f2bf(b.y*KSCALE);
      qv[6]=(short)f2bf(b.z*KSCALE); qv[7]=(short)f2bf(b.w*KSCALE);
      qf[h] = qv;
    }
  }

  issue(0, smem[0]);   // prologue

  v4f zero = {0.f, 0.f, 0.f, 0.f};
  v4f acc[4];
  acc[0] = zero; acc[1] = zero; acc[2] = zero; acc[3] = zero;
  float m = -INFINITY, l = 0.f;   // l lane-partial; reduced in epilogue

  for (int t = 0; t < M; ++t){
    const int tn = (t + 1 < M) ? t + 1 : t;
    issue(tn, smem[(t + 1) & 1]);                    // prefetch next tile
    asm volatile("s_waitcnt vmcnt(2)" ::: "memory"); // current tile landed
    __builtin_amdgcn_s_barrier();
    __builtin_amdgcn_sched_barrier(0);

    if (t <= qt){
      const char* kbase = smem[t & 1];
      const char* vbase = smem[t & 1] + 8192;

      // ---- S^T = K * Q^T ----
      float p4[4][4];
      __builtin_amdgcn_s_setprio(1);
      #pragma unroll
      for (int kb = 0; kb < 4; ++kb){
        v4f st = zero;
        v8s k0 = *(const v8s*)(kbase + kb * 2048 +        lane * 16);
        v8s k1 = *(const v8s*)(kbase + kb * 2048 + 1024 + lane * 16);
        st = __builtin_amdgcn_mfma_f32_16x16x32_bf16(k0, qf[0], st, 0, 0, 0);
        st = __builtin_amdgcn_mfma_f32_16x16x32_bf16(k1, qf[1], st, 0, 0, 0);
        p4[kb][0] = st[0]; p4[kb][1] = st[1]; p4[kb][2] = st[2]; p4[kb][3] = st[3];
      }
      __builtin_amdgcn_s_setprio(0);

      if (t == qt){   // diagonal tile: causal mask
        #pragma unroll
        for (int kb = 0; kb < 4; ++kb){
          #pragma unroll
          for (int r = 0; r < 4; ++r){
            const int krow = t * 64 + kb * 16 + g * 4 + r;
            if (krow > qw0 + lq) p4[kb][r] = -INFINITY;
          }
        }
      }

      // tree max + cross-group reduce
      float mx[4];
      #pragma unroll
      for (int kb = 0; kb < 4; ++kb)
        mx[kb] = fmaxf(fmaxf(p4[kb][0], p4[kb][1]), fmaxf(p4[kb][2], p4[kb][3]));
      float pmax = fmaxf(fmaxf(mx[0], mx[1]), fmaxf(mx[2], mx[3]));
      pmax = fmaxf(pmax, __shfl_xor(pmax, 16));
      pmax = fmaxf(pmax, __shfl_xor(pmax, 32));

      // online update with defer-max (THR=8, log2 domain)
      if (!__all(pmax - m <= 8.0f)){
        const float mn = fmaxf(m, pmax);
        const float sf = exp2f(m - mn);
        #pragma unroll
        for (int db = 0; db < 4; ++db) acc[db] *= sf;
        l *= sf;
        m = mn;
      }
      #pragma unroll
      for (int kb = 0; kb < 4; ++kb){
        #pragma unroll
        for (int r = 0; r < 4; ++r){
          const float pe = exp2f(p4[kb][r] - m);   // masked -> 0
          p4[kb][r] = pe;
          l += pe;
        }
      }

      // ---- O^T += V^T * P^T (P in registers, packed via v_cvt_pk) ----
      __builtin_amdgcn_s_setprio(1);
      #pragma unroll
      for (int kp = 0; kp < 2; ++kp){
        unsigned u0, u1, u2, u3;
        asm("v_cvt_pk_bf16_f32 %0, %1, %2" : "=v"(u0) : "v"(p4[2*kp  ][0]), "v"(p4[2*kp  ][1]));
        asm("v_cvt_pk_bf16_f32 %0, %1, %2" : "=v"(u1) : "v"(p4[2*kp  ][2]), "v"(p4[2*kp  ][3]));
        asm("v_cvt_pk_bf16_f32 %0, %1, %2" : "=v"(u2) : "v"(p4[2*kp+1][0]), "v"(p4[2*kp+1][1]));
        asm("v_cvt_pk_bf16_f32 %0, %1, %2" : "=v"(u3) : "v"(p4[2*kp+1][2]), "v"(p4[2*kp+1][3]));
        union { unsigned u[2]; v4s s; } P0, P1;
        P0.u[0] = u0; P0.u[1] = u1;
        P1.u[0] = u2; P1.u[1] = u3;
        #pragma unroll
        for (int db = 0; db < 4; ++db){
          v8s vv = *(const v8s*)(vbase + (db * 2 + kp) * 1024 + lane * 16);
          v4s va0 = {vv[0], vv[1], vv[2], vv[3]};
          v4s va1 = {vv[4], vv[5], vv[6], vv[7]};
          acc[db] = __builtin_amdgcn_mfma_f32_16x16x16bf16_1k(va0, P0.s, acc[db], 0, 0, 0);
          acc[db] = __builtin_amdgcn_mfma_f32_16x16x16bf16_1k(va1, P1.s, acc[db], 0, 0, 0);
        }
      }
      __builtin_amdgcn_s_setprio(0);
    }
    __builtin_amdgcn_s_barrier();
    __builtin_amdgcn_sched_barrier(0);
  }

  // epilogue: reduce l across lane-groups, store O^T fragment and L
  l += __shfl_xor(l, 16);
  l += __shfl_xor(l, 32);
  const float invl = 1.f / l;
  float* Op = O + ((size_t)bh * S_LEN + qw0 + lq) * DH + g * 4;
  #pragma unroll
  for (int db = 0; db < 4; ++db){
    v4f o = acc[db] * invl;
    *(v4f*)(Op + db * 16) = o;
  }
  if (g == 0)
    L[(size_t)bh * S_LEN + qw0 + lq] = m * LN2 + logf(l);
}

// ---------------- naive fallback (only if ws too small) ----------------
__global__ __launch_bounds__(64) void fa_naive(
    const float* __restrict__ Q, const float* __restrict__ K,
    const float* __restrict__ V, float* __restrict__ O, float* __restrict__ L)
{
  const int q  = blockIdx.x;
  const int bh = blockIdx.y;
  const int d  = threadIdx.x;
  const float qv = Q[(size_t)(bh * S_LEN + q) * DH + d];
  float m = -INFINITY, l = 0.f, o = 0.f;
  for (int k = 0; k <= q; ++k){
    float s = qv * K[(size_t)(bh * S_LEN + k) * DH + d];
    #pragma unroll
    for (int off = 32; off > 0; off >>= 1) s += __shfl_xor(s, off);
    s *= 0.125f;
    const float mn = fmaxf(m, s);
    const float sfc = expf(m - mn);
    const float pe = expf(s - mn);
    l = l * sfc + pe;
    o = o * sfc + pe * V[(size_t)(bh * S_LEN + k) * DH + d];
    m = mn;
  }
  O[(size_t)(bh * S_LEN + q) * DH + d] = o / l;
  if (d == 0) L[(size_t)bh * S_LEN + q] = m + logf(l);
}

extern "C" void kernel_launch(void* const* d_in, const int* in_sizes, int n_in,
                              void* d_out, int out_size, void* d_ws, size_t ws_size,
                              hipStream_t stream)
{
  (void)in_sizes; (void)n_in; (void)out_size;
  const float* Q = (const float*)d_in[0];
  const float* K = (const float*)d_in[1];
  const float* V = (const float*)d_in[2];
  float* O = (float*)d_out;
  float* L = O + (size_t)NBH * S_LEN * DH;

  const size_t half = (size_t)NBH * S_LEN * DH * sizeof(unsigned short); // 8 MiB
  if (ws_size >= 2 * half){
    unsigned short* Kf = (unsigned short*)d_ws;
    unsigned short* Vf = Kf + (size_t)NBH * S_LEN * DH;
    prep<<<dim3(S_LEN / 64, NBH), 256, 0, stream>>>(K, V, Kf, Vf);
    fa_fwd<<<dim3(NBH, 16), 512, 0, stream>>>(Q, Kf, Vf, O, L);
  } else {
    fa_naive<<<dim3(S_LEN, NBH), 64, 0, stream>>>(Q, K, V, O, L);
  }
}